// Round 1
// baseline (485.082 us; speedup 1.0000x reference)
//
#include <hip/hip_runtime.h>
#include <hip/hip_bf16.h>

// Problem constants (fixed by setup_inputs)
#define Bq 2
#define Lq 2048
#define BLq (Bq*Lq)          // 4096
#define KNB 48
#define NA 14
#define NTOK 21
#define NRBF 16
#define POSD 16
#define EOUT 128
#define KDIM 416             // 16 pos + 400 rbf = 13*32
#define ASTRIDE 424          // padded row stride (bf16 elems), 848B = 53*16B
#define ESTRIDE 132          // padded fp32 row stride for LN staging
#define E_ELEMS (BLq*KNB*EOUT)   // 25165824

typedef __attribute__((ext_vector_type(8))) short short8;
typedef __attribute__((ext_vector_type(4))) float f32x4;

__device__ __forceinline__ unsigned short bf16_rn(float x) {
    unsigned int u = __float_as_uint(x);
    unsigned int r = (u + 0x7fffu + ((u >> 16) & 1u)) >> 16;
    return (unsigned short)r;
}

// ---------------- Kernel A: X_all = [N, CA, C, O(4th), Xv] ----------------
__global__ void xall_kernel(const float* __restrict__ X, const int* __restrict__ S,
                            const int* __restrict__ table, float* __restrict__ Xall) {
    int t = blockIdx.x * blockDim.x + threadIdx.x;
    if (t >= BLq) return;
    int s = S[t];
    float bb[4][3];
#pragma unroll
    for (int a = 0; a < 4; ++a) {
        int ia = table[s * 4 + a];
#pragma unroll
        for (int d = 0; d < 3; ++d) bb[a][d] = X[(t * NA + ia) * 3 + d];
    }
    float b1[3], b2[3], nr[3];
#pragma unroll
    for (int d = 0; d < 3; ++d) { b1[d] = bb[0][d] - bb[1][d]; b2[d] = bb[2][d] - bb[1][d]; }
    nr[0] = b1[1] * b2[2] - b1[2] * b2[1];
    nr[1] = b1[2] * b2[0] - b1[0] * b2[2];
    nr[2] = b1[0] * b2[1] - b1[1] * b2[0];
#pragma unroll
    for (int a = 0; a < 4; ++a)
#pragma unroll
        for (int d = 0; d < 3; ++d) Xall[t * 15 + a * 3 + d] = bb[a][d];
#pragma unroll
    for (int d = 0; d < 3; ++d) {
        float xv = 0.58273431f * nr[d] + (-0.56802827f) * b1[d] + (-0.54067466f) * b2[d] + bb[1][d];
        Xall[t * 15 + 12 + d] = xv;
    }
}

// ---------------- Kernel B: pack W_e (416x128) into MFMA B-fragment order, bf16 ----
// Wp[((kt*8+nt)*64+lane)*8+j] = bf16(We[(kt*32+(lane>>4)*8+j)*128 + nt*16+(lane&15)])
__global__ void pack_kernel(const float* __restrict__ We, short* __restrict__ Wp) {
    int t = blockIdx.x * 256 + threadIdx.x;
    if (t >= 13 * 8 * 64 * 8) return;
    int j = t & 7;
    int lane = (t >> 3) & 63;
    int nt = (t >> 9) & 7;
    int kt = t >> 12;
    int k = kt * 32 + (lane >> 4) * 8 + j;
    int n = nt * 16 + (lane & 15);
    Wp[t] = (short)bf16_rn(We[k * 128 + n]);
}

// ---------------- Kernel T: exact 48-NN per query via bitonic sort of (D,idx) -----
__global__ __launch_bounds__(256) void topk_kernel(const float* __restrict__ Xall,
                                                   const float* __restrict__ mask,
                                                   int* __restrict__ eidx_ws,
                                                   float* __restrict__ out_idx) {
    __shared__ unsigned long long keys[Lq];
    int bl = blockIdx.x;
    int b = bl >> 11;
    int base = b << 11;
    float qx = Xall[bl * 15 + 3], qy = Xall[bl * 15 + 4], qz = Xall[bl * 15 + 5];
    float mq = mask[bl];
    for (int j = threadIdx.x; j < Lq; j += 256) {
        int row = base + j;
        float dx = __fsub_rn(qx, Xall[row * 15 + 3]);
        float dy = __fsub_rn(qy, Xall[row * 15 + 4]);
        float dz = __fsub_rn(qz, Xall[row * 15 + 5]);
        // match numpy: ((dx*dx + dy*dy) + dz*dz) + 1e-6, no FMA contraction
        float s = __fadd_rn(__fadd_rn(__fmul_rn(dx, dx), __fmul_rn(dy, dy)), __fmul_rn(dz, dz));
        float D = __fsqrt_rn(__fadd_rn(s, 1e-6f));
        float m2 = __fmul_rn(mq, mask[row]);
        float Dadj = __fadd_rn(__fmul_rn(D, m2), __fmul_rn(__fsub_rn(1.0f, m2), 1000000.0f));
        keys[j] = (((unsigned long long)__float_as_uint(Dadj)) << 32) | (unsigned int)j;
    }
    __syncthreads();
    // bitonic ascending sort of 2048 u64 keys
    for (int k = 2; k <= Lq; k <<= 1) {
        for (int jj = k >> 1; jj > 0; jj >>= 1) {
            for (int e = threadIdx.x; e < Lq; e += 256) {
                int p = e ^ jj;
                if (p > e) {
                    bool up = ((e & k) == 0);
                    unsigned long long a = keys[e], bv = keys[p];
                    if ((a > bv) == up) { keys[e] = bv; keys[p] = a; }
                }
            }
            __syncthreads();
        }
    }
    if (threadIdx.x < KNB) {
        int j = (int)(keys[threadIdx.x] & 0xffffffffu);
        eidx_ws[bl * KNB + threadIdx.x] = j;
        out_idx[bl * KNB + threadIdx.x] = (float)j;
    }
}

// ---------------- Kernel C: features -> MFMA GEMM (48x416 @ 416x128) -> LayerNorm ----
__global__ __launch_bounds__(256) void edge_kernel(
    const float* __restrict__ Xall, const int* __restrict__ eidx_ws,
    const int* __restrict__ ridx, const float* __restrict__ Wpos,
    const float* __restrict__ bpos, const short* __restrict__ Wp,
    const float* __restrict__ lng, const float* __restrict__ lnb,
    float* __restrict__ out) {
    __shared__ __align__(16) unsigned short Asm[KNB * ASTRIDE];  // 40704 B, overlaid by Esm later
    __shared__ float Dsm[KNB * 25];
    __shared__ float Xq[16];
    __shared__ float Xn[KNB * 15];
    __shared__ int eidxs[KNB];
    __shared__ int offs[KNB];

    int bl = blockIdx.x;
    int b = bl >> 11;
    int tid = threadIdx.x;

    // phase 0: neighbor indices, relative-position offsets, query atoms
    if (tid < KNB) {
        int j = eidx_ws[bl * KNB + tid];
        eidxs[tid] = j;
        int off = ridx[bl] - ridx[(b << 11) + j] + 32;
        off = min(max(off, 0), 64);
        offs[tid] = off;
    }
    if (tid < 15) Xq[tid] = Xall[bl * 15 + tid];
    __syncthreads();

    // phase 1: stage neighbor atoms
    for (int f = tid; f < KNB * 15; f += 256) {
        int k = f / 15, d = f - k * 15;
        Xn[f] = Xall[((b << 11) + eidxs[k]) * 15 + d];
    }
    __syncthreads();

    // phase 2: 48*25 pairwise atom distances
    for (int f = tid; f < KNB * 25; f += 256) {
        int k = f / 25, p = f - k * 25;
        int a = p / 5, c = p - a * 5;
        float dx = Xq[a * 3 + 0] - Xn[k * 15 + c * 3 + 0];
        float dy = Xq[a * 3 + 1] - Xn[k * 15 + c * 3 + 1];
        float dz = Xq[a * 3 + 2] - Xn[k * 15 + c * 3 + 2];
        Dsm[f] = sqrtf(dx * dx + dy * dy + dz * dz + 1e-6f);
    }
    __syncthreads();

    // phase 3: fill bf16 feature tile A[48][416]: [0,16)=pos (W_pos row + b_pos), [16,416)=RBF
    for (int f = tid; f < KNB * KDIM; f += 256) {
        int k = f / KDIM, c = f - k * KDIM;
        float val;
        if (c < 16) {
            val = Wpos[offs[k] * 16 + c] + bpos[c];
        } else {
            int cc = c - 16;
            int pr = cc >> 4, r = cc & 15;
            float D = Dsm[k * 25 + pr];
            float mu = 2.0f + (float)r * (20.0f / 15.0f);
            float t = (D - mu) * 0.8f;   // /1.25
            val = __expf(-t * t);
        }
        Asm[k * ASTRIDE + c] = bf16_rn(val);
    }
    __syncthreads();

    // phase 4: MFMA. wave w handles n-tiles {2w,2w+1}, m-tiles 0..2
    int w = tid >> 6, lane = tid & 63;
    int quad = lane >> 4, lr = lane & 15;
    f32x4 acc[3][2];
#pragma unroll
    for (int mt = 0; mt < 3; ++mt)
#pragma unroll
        for (int nt = 0; nt < 2; ++nt) acc[mt][nt] = (f32x4){0.f, 0.f, 0.f, 0.f};

    for (int kt = 0; kt < 13; ++kt) {
        short8 bf0 = *(const short8*)(Wp + (((kt * 8 + 2 * w + 0) * 64 + lane) << 3));
        short8 bf1 = *(const short8*)(Wp + (((kt * 8 + 2 * w + 1) * 64 + lane) << 3));
#pragma unroll
        for (int mt = 0; mt < 3; ++mt) {
            short8 af = *(const short8*)(&Asm[(mt * 16 + lr) * ASTRIDE + kt * 32 + quad * 8]);
            acc[mt][0] = __builtin_amdgcn_mfma_f32_16x16x32_bf16(af, bf0, acc[mt][0], 0, 0, 0);
            acc[mt][1] = __builtin_amdgcn_mfma_f32_16x16x32_bf16(af, bf1, acc[mt][1], 0, 0, 0);
        }
    }
    __syncthreads();   // all A reads done before overlaying Esm

    // phase 5: stage pre-LN E in LDS (overlay on Asm)
    float* Esm = (float*)Asm;
#pragma unroll
    for (int mt = 0; mt < 3; ++mt)
#pragma unroll
        for (int ntl = 0; ntl < 2; ++ntl) {
            int col = (2 * w + ntl) * 16 + lr;
#pragma unroll
            for (int r = 0; r < 4; ++r) {
                int row = mt * 16 + quad * 4 + r;
                Esm[row * ESTRIDE + col] = acc[mt][ntl][r];
            }
        }
    __syncthreads();

    // phase 6: LayerNorm per edge row (wave per row), coalesced store
    float g0 = lng[lane], g1 = lng[lane + 64];
    float bb0 = lnb[lane], bb1 = lnb[lane + 64];
    for (int r = w; r < KNB; r += 4) {
        float v0 = Esm[r * ESTRIDE + lane];
        float v1 = Esm[r * ESTRIDE + lane + 64];
        float s = v0 + v1;
#pragma unroll
        for (int o = 32; o > 0; o >>= 1) s += __shfl_xor(s, o);
        float mean = s * (1.0f / 128.0f);
        float d0 = v0 - mean, d1 = v1 - mean;
        float sq = d0 * d0 + d1 * d1;
#pragma unroll
        for (int o = 32; o > 0; o >>= 1) sq += __shfl_xor(sq, o);
        float inv = rsqrtf(sq * (1.0f / 128.0f) + 1e-5f);
        int ob = (bl * KNB + r) * EOUT;
        out[ob + lane] = d0 * inv * g0 + bb0;
        out[ob + lane + 64] = d1 * inv * g1 + bb1;
    }
}

extern "C" void kernel_launch(void* const* d_in, const int* in_sizes, int n_in,
                              void* d_out, int out_size, void* d_ws, size_t ws_size,
                              hipStream_t stream) {
    const float* X    = (const float*)d_in[0];
    // d_in[1] = X_m (unused by reference)
    const int*   S    = (const int*)d_in[2];
    const int*   ridx = (const int*)d_in[3];
    const float* mask = (const float*)d_in[4];
    const int*   tab  = (const int*)d_in[5];
    const float* Wpos = (const float*)d_in[6];
    const float* bpos = (const float*)d_in[7];
    const float* We   = (const float*)d_in[8];
    const float* lng  = (const float*)d_in[9];
    const float* lnb  = (const float*)d_in[10];
    float* out = (float*)d_out;

    char* ws = (char*)d_ws;
    float* Xall = (float*)ws;                         // 4096*15*4   = 245760 B
    int*   eidx = (int*)(ws + 245760);                // 196608*4    = 786432 B
    short* Wp   = (short*)(ws + 245760 + 786432);     // 53248*2     = 106496 B

    xall_kernel<<<16, 256, 0, stream>>>(X, S, tab, Xall);
    pack_kernel<<<208, 256, 0, stream>>>(We, Wp);
    topk_kernel<<<BLq, 256, 0, stream>>>(Xall, mask, eidx, out + E_ELEMS);
    edge_kernel<<<BLq, 256, 0, stream>>>(Xall, eidx, ridx, Wpos, bpos, Wp, lng, lnb, out);
}

// Round 2
// 279.473 us; speedup vs baseline: 1.7357x; 1.7357x over previous
//
#include <hip/hip_runtime.h>
#include <hip/hip_bf16.h>

// Problem constants (fixed by setup_inputs)
#define Bq 2
#define Lq 2048
#define BLq (Bq*Lq)          // 4096
#define KNB 48
#define NA 14
#define NTOK 21
#define NRBF 16
#define POSD 16
#define EOUT 128
#define KDIM 416             // 16 pos + 400 rbf = 13*32
#define ASTRIDE 424          // padded row stride (bf16 elems), 848B = 53*16B
#define ESTRIDE 132          // padded fp32 row stride for LN staging
#define E_ELEMS (BLq*KNB*EOUT)   // 25165824

typedef __attribute__((ext_vector_type(8))) short short8;
typedef __attribute__((ext_vector_type(4))) float f32x4;

__device__ __forceinline__ unsigned short bf16_rn(float x) {
    unsigned int u = __float_as_uint(x);
    unsigned int r = (u + 0x7fffu + ((u >> 16) & 1u)) >> 16;
    return (unsigned short)r;
}

// ---------------- Kernel A: X_all = [N, CA, C, O(4th), Xv]; CA4 = (CA.xyz, mask) ----
__global__ void xall_kernel(const float* __restrict__ X, const int* __restrict__ S,
                            const int* __restrict__ table, const float* __restrict__ mask,
                            float* __restrict__ Xall, float4* __restrict__ CA4) {
    int t = blockIdx.x * blockDim.x + threadIdx.x;
    if (t >= BLq) return;
    int s = S[t];
    float bb[4][3];
#pragma unroll
    for (int a = 0; a < 4; ++a) {
        int ia = table[s * 4 + a];
#pragma unroll
        for (int d = 0; d < 3; ++d) bb[a][d] = X[(t * NA + ia) * 3 + d];
    }
    float b1[3], b2[3], nr[3];
#pragma unroll
    for (int d = 0; d < 3; ++d) { b1[d] = bb[0][d] - bb[1][d]; b2[d] = bb[2][d] - bb[1][d]; }
    nr[0] = b1[1] * b2[2] - b1[2] * b2[1];
    nr[1] = b1[2] * b2[0] - b1[0] * b2[2];
    nr[2] = b1[0] * b2[1] - b1[1] * b2[0];
#pragma unroll
    for (int a = 0; a < 4; ++a)
#pragma unroll
        for (int d = 0; d < 3; ++d) Xall[t * 15 + a * 3 + d] = bb[a][d];
#pragma unroll
    for (int d = 0; d < 3; ++d) {
        float xv = 0.58273431f * nr[d] + (-0.56802827f) * b1[d] + (-0.54067466f) * b2[d] + bb[1][d];
        Xall[t * 15 + 12 + d] = xv;
    }
    CA4[t] = make_float4(bb[1][0], bb[1][1], bb[1][2], mask[t]);
}

// ---------------- Kernel B: pack W_e (416x128) into MFMA B-fragment order, bf16 ----
__global__ void pack_kernel(const float* __restrict__ We, short* __restrict__ Wp) {
    int t = blockIdx.x * 256 + threadIdx.x;
    if (t >= 13 * 8 * 64 * 8) return;
    int j = t & 7;
    int lane = (t >> 3) & 63;
    int nt = (t >> 9) & 7;
    int kt = t >> 12;
    int k = kt * 32 + (lane >> 4) * 8 + j;
    int n = nt * 16 + (lane & 15);
    Wp[t] = (short)bf16_rn(We[k * 128 + n]);
}

// ---------------- Kernel T: exact 48-NN per query via MSB-first radix select -----
// key = (u64(f32_bits(D_adj)) << 16) | idx  -- keys distinct, ascending order
// matches lax.top_k(-D_adj) tie-breaking (lower index first on equal D).
__global__ __launch_bounds__(256) void topk_kernel(const float4* __restrict__ CA4,
                                                   int* __restrict__ eidx_ws,
                                                   float* __restrict__ out_idx) {
    __shared__ unsigned int hist[256];
    __shared__ unsigned long long buf[128];
    __shared__ unsigned int nacc;
    __shared__ int sh_bin, sh_excl, sh_cnt;

    int bl = blockIdx.x;
    int base = (bl >> 11) << 11;
    int tid = threadIdx.x;
    float4 q = CA4[bl];

    unsigned long long key[8];
#pragma unroll
    for (int i = 0; i < 8; ++i) {
        int j = tid + (i << 8);
        float4 c = CA4[base + j];
        float dx = __fsub_rn(q.x, c.x);
        float dy = __fsub_rn(q.y, c.y);
        float dz = __fsub_rn(q.z, c.z);
        // match numpy: ((dx*dx + dy*dy) + dz*dz) + 1e-6, no FMA contraction
        float s = __fadd_rn(__fadd_rn(__fmul_rn(dx, dx), __fmul_rn(dy, dy)), __fmul_rn(dz, dz));
        float D = __fsqrt_rn(__fadd_rn(s, 1e-6f));
        float m2 = __fmul_rn(q.w, c.w);
        float Dadj = __fadd_rn(__fmul_rn(D, m2), __fmul_rn(__fsub_rn(1.0f, m2), 1000000.0f));
        key[i] = (((unsigned long long)__float_as_uint(Dadj)) << 16) | (unsigned int)j;
    }

    unsigned long long prefix = 0;
    int need = 48, cnt = 0, shift = 40;
    for (;;) {
        hist[tid] = 0;
        __syncthreads();
#pragma unroll
        for (int i = 0; i < 8; ++i)
            if ((key[i] >> (shift + 8)) == prefix)
                atomicAdd(&hist[(unsigned int)((key[i] >> shift) & 255ull)], 1u);
        __syncthreads();
        if (tid < 64) {
            unsigned int h0 = hist[4 * tid + 0], h1 = hist[4 * tid + 1];
            unsigned int h2 = hist[4 * tid + 2], h3 = hist[4 * tid + 3];
            unsigned int s4 = h0 + h1 + h2 + h3;
            unsigned int incl = s4;
#pragma unroll
            for (int o = 1; o < 64; o <<= 1) {
                unsigned int v = __shfl_up(incl, o);
                if (tid >= o) incl += v;
            }
            unsigned int excl = incl - s4;
            if ((int)excl < need && need <= (int)incl) {   // exactly one lane
                unsigned int cb = excl;
                unsigned int hh[4] = {h0, h1, h2, h3};
                int bsel = 3;
#pragma unroll
                for (int bb2 = 0; bb2 < 4; ++bb2) {
                    if ((int)(cb + hh[bb2]) >= need) { bsel = bb2; break; }
                    cb += hh[bb2];
                }
                sh_bin = 4 * tid + bsel;
                sh_excl = (int)cb;
                sh_cnt = (int)hh[bsel];
            }
        }
        __syncthreads();
        prefix = (prefix << 8) | (unsigned long long)(unsigned int)sh_bin;
        need -= sh_excl;
        cnt = sh_cnt;
        if (cnt <= 80 || shift == 0) break;
        shift -= 8;
    }

    // collect: all keys with (key>>shift) <= prefix  ->  (48-need) definite + cnt candidates <= 127
    if (tid == 0) nacc = 0;
    __syncthreads();
#pragma unroll
    for (int i = 0; i < 8; ++i) {
        if ((key[i] >> shift) <= prefix) {
            unsigned int p = atomicAdd(&nacc, 1u);
            if (p < 128) buf[p] = key[i];
        }
    }
    __syncthreads();
    unsigned int m = nacc;
    if (tid < 128 && tid >= m) buf[tid] = ~0ULL;
    __syncthreads();

    // rank by all-pairs count (keys distinct -> exact rank), write first 48
    if (tid < 128) {
        unsigned long long k = buf[tid];
        int rank = 0;
        for (int u = 0; u < 128; ++u) rank += (buf[u] < k) ? 1 : 0;
        if (rank < KNB) {
            int j = (int)(k & 0xffffull);
            eidx_ws[bl * KNB + rank] = j;
            out_idx[bl * KNB + rank] = (float)j;
        }
    }
}

// ---------------- Kernel C: features -> MFMA GEMM (48x416 @ 416x128) -> LayerNorm ----
__global__ __launch_bounds__(256) void edge_kernel(
    const float* __restrict__ Xall, const int* __restrict__ eidx_ws,
    const int* __restrict__ ridx, const float* __restrict__ Wpos,
    const float* __restrict__ bpos, const short* __restrict__ Wp,
    const float* __restrict__ lng, const float* __restrict__ lnb,
    float* __restrict__ out) {
    __shared__ __align__(16) unsigned short Asm[KNB * ASTRIDE];  // 40704 B, overlaid by Esm later
    __shared__ float Dsm[KNB * 25];
    __shared__ float Xq[16];
    __shared__ float Xn[KNB * 15];
    __shared__ int eidxs[KNB];
    __shared__ int offs[KNB];

    int bl = blockIdx.x;
    int b = bl >> 11;
    int tid = threadIdx.x;

    // phase 0: neighbor indices, relative-position offsets, query atoms
    if (tid < KNB) {
        int j = eidx_ws[bl * KNB + tid];
        eidxs[tid] = j;
        int off = ridx[bl] - ridx[(b << 11) + j] + 32;
        off = min(max(off, 0), 64);
        offs[tid] = off;
    }
    if (tid < 15) Xq[tid] = Xall[bl * 15 + tid];
    __syncthreads();

    // phase 1: stage neighbor atoms
    for (int f = tid; f < KNB * 15; f += 256) {
        int k = f / 15, d = f - k * 15;
        Xn[f] = Xall[((b << 11) + eidxs[k]) * 15 + d];
    }
    __syncthreads();

    // phase 2: 48*25 pairwise atom distances
    for (int f = tid; f < KNB * 25; f += 256) {
        int k = f / 25, p = f - k * 25;
        int a = p / 5, c = p - a * 5;
        float dx = Xq[a * 3 + 0] - Xn[k * 15 + c * 3 + 0];
        float dy = Xq[a * 3 + 1] - Xn[k * 15 + c * 3 + 1];
        float dz = Xq[a * 3 + 2] - Xn[k * 15 + c * 3 + 2];
        Dsm[f] = sqrtf(dx * dx + dy * dy + dz * dz + 1e-6f);
    }
    __syncthreads();

    // phase 3: fill bf16 feature tile A[48][416]: [0,16)=pos (W_pos row + b_pos), [16,416)=RBF
    for (int f = tid; f < KNB * KDIM; f += 256) {
        int k = f / KDIM, c = f - k * KDIM;
        float val;
        if (c < 16) {
            val = Wpos[offs[k] * 16 + c] + bpos[c];
        } else {
            int cc = c - 16;
            int pr = cc >> 4, r = cc & 15;
            float D = Dsm[k * 25 + pr];
            float mu = 2.0f + (float)r * (20.0f / 15.0f);
            float t = (D - mu) * 0.8f;   // /1.25
            val = __expf(-t * t);
        }
        Asm[k * ASTRIDE + c] = bf16_rn(val);
    }
    __syncthreads();

    // phase 4: MFMA. wave w handles n-tiles {2w,2w+1}, m-tiles 0..2
    int w = tid >> 6, lane = tid & 63;
    int quad = lane >> 4, lr = lane & 15;
    f32x4 acc[3][2];
#pragma unroll
    for (int mt = 0; mt < 3; ++mt)
#pragma unroll
        for (int nt = 0; nt < 2; ++nt) acc[mt][nt] = (f32x4){0.f, 0.f, 0.f, 0.f};

    for (int kt = 0; kt < 13; ++kt) {
        short8 bf0 = *(const short8*)(Wp + (((kt * 8 + 2 * w + 0) * 64 + lane) << 3));
        short8 bf1 = *(const short8*)(Wp + (((kt * 8 + 2 * w + 1) * 64 + lane) << 3));
#pragma unroll
        for (int mt = 0; mt < 3; ++mt) {
            short8 af = *(const short8*)(&Asm[(mt * 16 + lr) * ASTRIDE + kt * 32 + quad * 8]);
            acc[mt][0] = __builtin_amdgcn_mfma_f32_16x16x32_bf16(af, bf0, acc[mt][0], 0, 0, 0);
            acc[mt][1] = __builtin_amdgcn_mfma_f32_16x16x32_bf16(af, bf1, acc[mt][1], 0, 0, 0);
        }
    }
    __syncthreads();   // all A reads done before overlaying Esm

    // phase 5: stage pre-LN E in LDS (overlay on Asm)
    float* Esm = (float*)Asm;
#pragma unroll
    for (int mt = 0; mt < 3; ++mt)
#pragma unroll
        for (int ntl = 0; ntl < 2; ++ntl) {
            int col = (2 * w + ntl) * 16 + lr;
#pragma unroll
            for (int r = 0; r < 4; ++r) {
                int row = mt * 16 + quad * 4 + r;
                Esm[row * ESTRIDE + col] = acc[mt][ntl][r];
            }
        }
    __syncthreads();

    // phase 6: LayerNorm per edge row (wave per row), coalesced store
    float g0 = lng[lane], g1 = lng[lane + 64];
    float bb0 = lnb[lane], bb1 = lnb[lane + 64];
    for (int r = w; r < KNB; r += 4) {
        float v0 = Esm[r * ESTRIDE + lane];
        float v1 = Esm[r * ESTRIDE + lane + 64];
        float s = v0 + v1;
#pragma unroll
        for (int o = 32; o > 0; o >>= 1) s += __shfl_xor(s, o);
        float mean = s * (1.0f / 128.0f);
        float d0 = v0 - mean, d1 = v1 - mean;
        float sq = d0 * d0 + d1 * d1;
#pragma unroll
        for (int o = 32; o > 0; o >>= 1) sq += __shfl_xor(sq, o);
        float inv = rsqrtf(sq * (1.0f / 128.0f) + 1e-5f);
        int ob = (bl * KNB + r) * EOUT;
        out[ob + lane] = d0 * inv * g0 + bb0;
        out[ob + lane + 64] = d1 * inv * g1 + bb1;
    }
}

extern "C" void kernel_launch(void* const* d_in, const int* in_sizes, int n_in,
                              void* d_out, int out_size, void* d_ws, size_t ws_size,
                              hipStream_t stream) {
    const float* X    = (const float*)d_in[0];
    // d_in[1] = X_m (unused by reference)
    const int*   S    = (const int*)d_in[2];
    const int*   ridx = (const int*)d_in[3];
    const float* mask = (const float*)d_in[4];
    const int*   tab  = (const int*)d_in[5];
    const float* Wpos = (const float*)d_in[6];
    const float* bpos = (const float*)d_in[7];
    const float* We   = (const float*)d_in[8];
    const float* lng  = (const float*)d_in[9];
    const float* lnb  = (const float*)d_in[10];
    float* out = (float*)d_out;

    char* ws = (char*)d_ws;
    float*  Xall = (float*)ws;                                  // 4096*15*4   = 245760 B
    int*    eidx = (int*)(ws + 245760);                         // 196608*4    = 786432 B
    short*  Wp   = (short*)(ws + 245760 + 786432);              // 53248*2     = 106496 B
    float4* CA4  = (float4*)(ws + 245760 + 786432 + 106496);    // 4096*16     = 65536 B

    xall_kernel<<<16, 256, 0, stream>>>(X, S, tab, mask, Xall, CA4);
    pack_kernel<<<208, 256, 0, stream>>>(We, Wp);
    topk_kernel<<<BLq, 256, 0, stream>>>(CA4, eidx, out + E_ELEMS);
    edge_kernel<<<BLq, 256, 0, stream>>>(Xall, eidx, ridx, Wpos, bpos, Wp, lng, lnb, out);
}

// Round 3
// 221.250 us; speedup vs baseline: 2.1925x; 1.2632x over previous
//
#include <hip/hip_runtime.h>
#include <hip/hip_bf16.h>

// Problem constants (fixed by setup_inputs)
#define Bq 2
#define Lq 2048
#define BLq (Bq*Lq)          // 4096
#define KNB 48
#define NA 14
#define NTOK 21
#define NRBF 16
#define POSD 16
#define EOUT 128
#define KDIM 416             // 16 pos + 400 rbf = 13*32
#define ASTRIDE 424          // padded row stride (bf16 elems), 848B = 53*16B
#define ESTRIDE 132          // padded fp32 row stride for LN staging
#define E_ELEMS (BLq*KNB*EOUT)   // 25165824

typedef __attribute__((ext_vector_type(8))) short short8;
typedef __attribute__((ext_vector_type(4))) float f32x4;

__device__ __forceinline__ unsigned short bf16_rn(float x) {
    unsigned int u = __float_as_uint(x);
    unsigned int r = (u + 0x7fffu + ((u >> 16) & 1u)) >> 16;
    return (unsigned short)r;
}

// ---------------- Kernel P: fused [xall (16 blocks)] + [W_e pack (208 blocks)] ----
__global__ void prep_kernel(const float* __restrict__ X, const int* __restrict__ S,
                            const int* __restrict__ table, const float* __restrict__ mask,
                            const float* __restrict__ We,
                            float* __restrict__ Xall, float4* __restrict__ CA4,
                            short* __restrict__ Wp) {
    int bid = blockIdx.x;
    if (bid < 16) {
        int t = bid * 256 + threadIdx.x;
        if (t >= BLq) return;
        int s = S[t];
        float bb[4][3];
#pragma unroll
        for (int a = 0; a < 4; ++a) {
            int ia = table[s * 4 + a];
#pragma unroll
            for (int d = 0; d < 3; ++d) bb[a][d] = X[(t * NA + ia) * 3 + d];
        }
        float b1[3], b2[3], nr[3];
#pragma unroll
        for (int d = 0; d < 3; ++d) { b1[d] = bb[0][d] - bb[1][d]; b2[d] = bb[2][d] - bb[1][d]; }
        nr[0] = b1[1] * b2[2] - b1[2] * b2[1];
        nr[1] = b1[2] * b2[0] - b1[0] * b2[2];
        nr[2] = b1[0] * b2[1] - b1[1] * b2[0];
#pragma unroll
        for (int a = 0; a < 4; ++a)
#pragma unroll
            for (int d = 0; d < 3; ++d) Xall[t * 15 + a * 3 + d] = bb[a][d];
#pragma unroll
        for (int d = 0; d < 3; ++d) {
            float xv = 0.58273431f * nr[d] + (-0.56802827f) * b1[d] + (-0.54067466f) * b2[d] + bb[1][d];
            Xall[t * 15 + 12 + d] = xv;
        }
        CA4[t] = make_float4(bb[1][0], bb[1][1], bb[1][2], mask[t]);
    } else {
        // pack W_e (416x128) into MFMA B-fragment order, bf16
        int t = (bid - 16) * 256 + threadIdx.x;
        if (t >= 13 * 8 * 64 * 8) return;
        int j = t & 7;
        int lane = (t >> 3) & 63;
        int nt = (t >> 9) & 7;
        int kt = t >> 12;
        int k = kt * 32 + (lane >> 4) * 8 + j;
        int n = nt * 16 + (lane & 15);
        Wp[t] = (short)bf16_rn(We[k * 128 + n]);
    }
}

// ---------------- Kernel T: exact 48-NN per query via MSB-first radix select -----
// key = (u64(f32_bits(D_adj)) << 16) | idx  -- keys distinct, ascending order
// matches lax.top_k(-D_adj) tie-breaking (lower index first on equal D).
__global__ __launch_bounds__(256) void topk_kernel(const float4* __restrict__ CA4,
                                                   int* __restrict__ eidx_ws,
                                                   float* __restrict__ out_idx) {
    __shared__ unsigned int hist[256];
    __shared__ unsigned long long buf[128];
    __shared__ unsigned int nacc;
    __shared__ int sh_bin, sh_excl, sh_cnt;

    int bl = blockIdx.x;
    int base = (bl >> 11) << 11;
    int tid = threadIdx.x;
    float4 q = CA4[bl];

    unsigned long long key[8];
#pragma unroll
    for (int i = 0; i < 8; ++i) {
        int j = tid + (i << 8);
        float4 c = CA4[base + j];
        float dx = __fsub_rn(q.x, c.x);
        float dy = __fsub_rn(q.y, c.y);
        float dz = __fsub_rn(q.z, c.z);
        // match numpy: ((dx*dx + dy*dy) + dz*dz) + 1e-6, no FMA contraction
        float s = __fadd_rn(__fadd_rn(__fmul_rn(dx, dx), __fmul_rn(dy, dy)), __fmul_rn(dz, dz));
        float D = __fsqrt_rn(__fadd_rn(s, 1e-6f));
        float m2 = __fmul_rn(q.w, c.w);
        float Dadj = __fadd_rn(__fmul_rn(D, m2), __fmul_rn(__fsub_rn(1.0f, m2), 1000000.0f));
        key[i] = (((unsigned long long)__float_as_uint(Dadj)) << 16) | (unsigned int)j;
    }

    unsigned long long prefix = 0;
    int need = 48, cnt = 0, shift = 40;
    for (;;) {
        hist[tid] = 0;
        __syncthreads();
#pragma unroll
        for (int i = 0; i < 8; ++i)
            if ((key[i] >> (shift + 8)) == prefix)
                atomicAdd(&hist[(unsigned int)((key[i] >> shift) & 255ull)], 1u);
        __syncthreads();
        if (tid < 64) {
            unsigned int h0 = hist[4 * tid + 0], h1 = hist[4 * tid + 1];
            unsigned int h2 = hist[4 * tid + 2], h3 = hist[4 * tid + 3];
            unsigned int s4 = h0 + h1 + h2 + h3;
            unsigned int incl = s4;
#pragma unroll
            for (int o = 1; o < 64; o <<= 1) {
                unsigned int v = __shfl_up(incl, o);
                if (tid >= o) incl += v;
            }
            unsigned int excl = incl - s4;
            if ((int)excl < need && need <= (int)incl) {   // exactly one lane
                unsigned int cb = excl;
                unsigned int hh[4] = {h0, h1, h2, h3};
                int bsel = 3;
#pragma unroll
                for (int bb2 = 0; bb2 < 4; ++bb2) {
                    if ((int)(cb + hh[bb2]) >= need) { bsel = bb2; break; }
                    cb += hh[bb2];
                }
                sh_bin = 4 * tid + bsel;
                sh_excl = (int)cb;
                sh_cnt = (int)hh[bsel];
            }
        }
        __syncthreads();
        prefix = (prefix << 8) | (unsigned long long)(unsigned int)sh_bin;
        need -= sh_excl;
        cnt = sh_cnt;
        if (cnt <= 80 || shift == 0) break;
        shift -= 8;
    }

    // collect: all keys with (key>>shift) <= prefix  ->  (48-need) definite + cnt candidates <= 127
    if (tid == 0) nacc = 0;
    __syncthreads();
#pragma unroll
    for (int i = 0; i < 8; ++i) {
        if ((key[i] >> shift) <= prefix) {
            unsigned int p = atomicAdd(&nacc, 1u);
            if (p < 128) buf[p] = key[i];
        }
    }
    __syncthreads();
    unsigned int m = nacc;
    if (tid < 128 && tid >= m) buf[tid] = ~0ULL;
    __syncthreads();

    // rank by all-pairs count (keys distinct -> exact rank), write first 48
    if (tid < 128) {
        unsigned long long k = buf[tid];
        int rank = 0;
        for (int u = 0; u < 128; ++u) rank += (buf[u] < k) ? 1 : 0;
        if (rank < KNB) {
            int j = (int)(k & 0xffffull);
            eidx_ws[bl * KNB + rank] = j;
            out_idx[bl * KNB + rank] = (float)j;
        }
    }
}

// ---------------- Kernel C: features -> MFMA GEMM (48x416 @ 416x128) -> LayerNorm ----
__global__ __launch_bounds__(256) void edge_kernel(
    const float* __restrict__ Xall, const int* __restrict__ eidx_ws,
    const int* __restrict__ ridx, const float* __restrict__ Wpos,
    const float* __restrict__ bpos, const short* __restrict__ Wp,
    const float* __restrict__ lng, const float* __restrict__ lnb,
    float* __restrict__ out) {
    __shared__ __align__(16) unsigned short Asm[KNB * ASTRIDE];  // 40704 B, overlaid by Esm later
    __shared__ float Dsm[KNB * 25];
    __shared__ float Xq[16];
    __shared__ float Xn[KNB * 15];
    __shared__ int offs[KNB];

    int bl = blockIdx.x;
    int b = bl >> 11;
    int tid = threadIdx.x;

    // phase 0+1: rel-pos offsets, query atoms, neighbor atom staging (one sync)
    if (tid < KNB) {
        int j = eidx_ws[bl * KNB + tid];
        int off = ridx[bl] - ridx[(b << 11) + j] + 32;
        offs[tid] = min(max(off, 0), 64);
    }
    if (tid < 15) Xq[tid] = Xall[bl * 15 + tid];
    for (int f = tid; f < KNB * 15; f += 256) {
        int k = f / 15, d = f - k * 15;
        int j = eidx_ws[bl * KNB + k];          // L1-hit broadcast re-read
        Xn[f] = Xall[((b << 11) + j) * 15 + d];
    }
    __syncthreads();

    // phase 2: 48*25 pairwise atom distances
    for (int f = tid; f < KNB * 25; f += 256) {
        int k = f / 25, p = f - k * 25;
        int a = p / 5, c = p - a * 5;
        float dx = Xq[a * 3 + 0] - Xn[k * 15 + c * 3 + 0];
        float dy = Xq[a * 3 + 1] - Xn[k * 15 + c * 3 + 1];
        float dz = Xq[a * 3 + 2] - Xn[k * 15 + c * 3 + 2];
        Dsm[f] = sqrtf(dx * dx + dy * dy + dz * dz + 1e-6f);
    }
    __syncthreads();

    // phase 3a: pos columns (cols 0..15), packed bf16x2 stores
#pragma unroll
    for (int i = 0; i < 2; ++i) {
        int t = tid + (i << 8);
        if (t < KNB * 8) {
            int k = t >> 3, cd = (t & 7) << 1;
            int off = offs[k];
            float v0 = Wpos[off * 16 + cd] + bpos[cd];
            float v1 = Wpos[off * 16 + cd + 1] + bpos[cd + 1];
            *(__hip_bfloat162*)&Asm[k * ASTRIDE + cd] = __float22bfloat162_rn(make_float2(v0, v1));
        }
    }
    // phase 3b: RBF columns (cols 16..415). thread -> fixed (pair, rbf-pair);
    // exp(-((D-mu)/1.25)^2) == exp2(-(((D-mu)*s1)^2)), s1 = 0.8*sqrt(log2 e)
    if (tid < 200) {
        int pr = tid >> 3;                 // atom-pair 0..24
        int r0 = (tid & 7) << 1;           // rbf index 0,2,..,14
        const float s1 = 0.96089795f;
        const float dlt = 1.28119727f;     // (20/15)*s1
        float c0 = (2.0f + 1.3333333f * (float)r0) * s1;
        unsigned short* arow = Asm + 16 + (tid << 1);
        const float* drow = Dsm + pr;
        for (int k = 0; k < KNB; ++k) {
            float D = drow[k * 25];
            float u0 = __builtin_fmaf(D, s1, -c0);
            float u1 = u0 - dlt;
            float v0 = __builtin_amdgcn_exp2f(-(u0 * u0));
            float v1 = __builtin_amdgcn_exp2f(-(u1 * u1));
            *(__hip_bfloat162*)(arow + k * ASTRIDE) = __float22bfloat162_rn(make_float2(v0, v1));
        }
    }
    __syncthreads();

    // phase 4: MFMA. wave w handles n-tiles {2w,2w+1}, m-tiles 0..2
    int w = tid >> 6, lane = tid & 63;
    int quad = lane >> 4, lr = lane & 15;
    f32x4 acc[3][2];
#pragma unroll
    for (int mt = 0; mt < 3; ++mt)
#pragma unroll
        for (int nt = 0; nt < 2; ++nt) acc[mt][nt] = (f32x4){0.f, 0.f, 0.f, 0.f};

    for (int kt = 0; kt < 13; ++kt) {
        short8 bf0 = *(const short8*)(Wp + (((kt * 8 + 2 * w + 0) * 64 + lane) << 3));
        short8 bf1 = *(const short8*)(Wp + (((kt * 8 + 2 * w + 1) * 64 + lane) << 3));
#pragma unroll
        for (int mt = 0; mt < 3; ++mt) {
            short8 af = *(const short8*)(&Asm[(mt * 16 + lr) * ASTRIDE + kt * 32 + quad * 8]);
            acc[mt][0] = __builtin_amdgcn_mfma_f32_16x16x32_bf16(af, bf0, acc[mt][0], 0, 0, 0);
            acc[mt][1] = __builtin_amdgcn_mfma_f32_16x16x32_bf16(af, bf1, acc[mt][1], 0, 0, 0);
        }
    }
    __syncthreads();   // all A reads done before overlaying Esm

    // phase 5: stage pre-LN E in LDS (overlay on Asm)
    float* Esm = (float*)Asm;
#pragma unroll
    for (int mt = 0; mt < 3; ++mt)
#pragma unroll
        for (int ntl = 0; ntl < 2; ++ntl) {
            int col = (2 * w + ntl) * 16 + lr;
#pragma unroll
            for (int r = 0; r < 4; ++r) {
                int row = mt * 16 + quad * 4 + r;
                Esm[row * ESTRIDE + col] = acc[mt][ntl][r];
            }
        }
    __syncthreads();

    // phase 6: LayerNorm per edge row (wave per row), one-pass var, coalesced store
    float g0 = lng[lane], g1 = lng[lane + 64];
    float bb0 = lnb[lane], bb1 = lnb[lane + 64];
    for (int r = w; r < KNB; r += 4) {
        float v0 = Esm[r * ESTRIDE + lane];
        float v1 = Esm[r * ESTRIDE + lane + 64];
        float s = v0 + v1;
        float qq = __builtin_fmaf(v0, v0, v1 * v1);
#pragma unroll
        for (int o = 32; o > 0; o >>= 1) { s += __shfl_xor(s, o); qq += __shfl_xor(qq, o); }
        float mean = s * 0.0078125f;
        float var = __builtin_fmaf(-mean, mean, qq * 0.0078125f);
        float inv = rsqrtf(var + 1e-5f);
        float a0 = inv * g0, a1 = inv * g1;
        int ob = (bl * KNB + r) * EOUT;
        out[ob + lane] = __builtin_fmaf(v0 - mean, a0, bb0);
        out[ob + lane + 64] = __builtin_fmaf(v1 - mean, a1, bb1);
    }
}

extern "C" void kernel_launch(void* const* d_in, const int* in_sizes, int n_in,
                              void* d_out, int out_size, void* d_ws, size_t ws_size,
                              hipStream_t stream) {
    const float* X    = (const float*)d_in[0];
    // d_in[1] = X_m (unused by reference)
    const int*   S    = (const int*)d_in[2];
    const int*   ridx = (const int*)d_in[3];
    const float* mask = (const float*)d_in[4];
    const int*   tab  = (const int*)d_in[5];
    const float* Wpos = (const float*)d_in[6];
    const float* bpos = (const float*)d_in[7];
    const float* We   = (const float*)d_in[8];
    const float* lng  = (const float*)d_in[9];
    const float* lnb  = (const float*)d_in[10];
    float* out = (float*)d_out;

    char* ws = (char*)d_ws;
    float*  Xall = (float*)ws;                                  // 4096*15*4   = 245760 B
    int*    eidx = (int*)(ws + 245760);                         // 196608*4    = 786432 B
    short*  Wp   = (short*)(ws + 245760 + 786432);              // 53248*2     = 106496 B
    float4* CA4  = (float4*)(ws + 245760 + 786432 + 106496);    // 4096*16     = 65536 B

    prep_kernel<<<224, 256, 0, stream>>>(X, S, tab, mask, We, Xall, CA4, Wp);
    topk_kernel<<<BLq, 256, 0, stream>>>(CA4, eidx, out + E_ELEMS);
    edge_kernel<<<BLq, 256, 0, stream>>>(Xall, eidx, ridx, Wpos, bpos, Wp, lng, lnb, out);
}